// Round 1
// baseline (182.089 us; speedup 1.0000x reference)
//
#include <hip/hip_runtime.h>
#include <hip/hip_bf16.h>

#define BT      8192
#define DIN     2048
#define DOUT    2048
#define NEXP    8
#define RANK    8
#define KX      2112         /* DIN + NEXP*RANK */
#define SCALING 1.0f         /* ALPHA / RANK = 8/8 */

typedef __bf16 bf16x8 __attribute__((ext_vector_type(8)));
typedef __bf16 bf16x4 __attribute__((ext_vector_type(4)));
typedef float  f32x4  __attribute__((ext_vector_type(4)));

/* ---- ws layout (bytes) ----
   XB   : [BT][KX]   bf16   (cols 0..2047 = bf16(x), cols 2048..2111 = g)
   WB   : [DOUT][KX] bf16   (cols 0..2047 = bf16(Wf), cols 2048..2111 = Bcat)
   ACAT : [128][DIN] bf16   (rows 0..7 = Wr, rows 8..71 = A[e][r], rows 72..127 = 0)
   HP   : [8][BT][128] f32  (K-split partials of xb @ ACAT^T)
   LOG  : [BT][8]    f32    (exact fp32 router logits)                       */
#define XB_OFF     0
#define XB_BYTES   (BT * KX * 2)
#define WB_OFF     (XB_OFF + XB_BYTES)
#define WB_BYTES   (DOUT * KX * 2)
#define ACAT_OFF   (WB_OFF + WB_BYTES)
#define ACAT_BYTES (128 * DIN * 2)
#define HP_OFF     (ACAT_OFF + ACAT_BYTES)
#define HP_BYTES   (8 * BT * 128 * 4)
#define LOG_OFF    (HP_OFF + HP_BYTES)

__device__ __forceinline__ void gload_lds16(const void* g, void* l) {
    __builtin_amdgcn_global_load_lds(
        (__attribute__((address_space(1))) void*)(g),
        (__attribute__((address_space(3))) void*)(l),
        16, 0, 0);
}

/* ---------------- prep: weights -> bf16 staged layouts ---------------- */
__global__ __launch_bounds__(256) void mole_prep(
    const float* __restrict__ Wf, const float* __restrict__ Bm,
    const float* __restrict__ Wr, const float* __restrict__ A,
    __bf16* __restrict__ WB, __bf16* __restrict__ ACAT)
{
    const int i = blockIdx.x * 256 + threadIdx.x;
    const int R1 = DOUT * (DIN / 4);       /* 1048576: Wf, float4-vectorized */
    const int R2 = DOUT * 64;              /* 131072 : Bcat scalar           */
    const int R3 = 128 * (DIN / 4);        /* 65536  : ACAT, float4          */
    if (i < R1) {
        const int o = i >> 9, c4 = i & 511;
        float4 v = ((const float4*)Wf)[(size_t)o * 512 + c4];
        bf16x4 b; b[0] = (__bf16)v.x; b[1] = (__bf16)v.y; b[2] = (__bf16)v.z; b[3] = (__bf16)v.w;
        *(bf16x4*)&WB[(size_t)o * KX + (c4 << 2)] = b;
    } else if (i < R1 + R2) {
        const int j = i - R1;
        const int o = j >> 6, c = j & 63;
        const int e = c >> 3, r = c & 7;
        WB[(size_t)o * KX + DIN + c] = (__bf16)Bm[((size_t)e * DOUT + o) * RANK + r];
    } else {
        const int j = i - (R1 + R2);
        const int r = j >> 9, c4 = j & 511;
        float4 v;
        if (r < 8)        v = ((const float4*)Wr)[(size_t)r * 512 + c4];
        else if (r < 72)  v = ((const float4*)A)[(size_t)(r - 8) * 512 + c4];
        else              v = make_float4(0.f, 0.f, 0.f, 0.f);
        bf16x4 b; b[0] = (__bf16)v.x; b[1] = (__bf16)v.y; b[2] = (__bf16)v.z; b[3] = (__bf16)v.w;
        *(bf16x4*)&ACAT[(size_t)r * DIN + (c4 << 2)] = b;
    }
}

/* ------- convert x -> bf16 (stride KX) + exact fp32 router logits ------- */
__global__ __launch_bounds__(512) void mole_convert_x_logits(
    const float* __restrict__ x, const float* __restrict__ Wr,
    const float* __restrict__ br,
    __bf16* __restrict__ XB, float* __restrict__ LOG)
{
    const int t   = blockIdx.x;          /* token */
    const int tid = threadIdx.x;         /* 512: one float4 each */
    float4 v = ((const float4*)x)[(size_t)t * 512 + tid];
    bf16x4 b; b[0] = (__bf16)v.x; b[1] = (__bf16)v.y; b[2] = (__bf16)v.z; b[3] = (__bf16)v.w;
    *(bf16x4*)&XB[(size_t)t * KX + (tid << 2)] = b;

    float p[NEXP];
    #pragma unroll
    for (int e = 0; e < NEXP; ++e) {
        float4 w4 = ((const float4*)Wr)[e * 512 + tid];
        p[e] = v.x * w4.x + v.y * w4.y + v.z * w4.z + v.w * w4.w;
    }
    #pragma unroll
    for (int e = 0; e < NEXP; ++e)
        #pragma unroll
        for (int off = 32; off > 0; off >>= 1)
            p[e] += __shfl_down(p[e], off);

    __shared__ float red[8][NEXP];
    const int wv = tid >> 6, ln = tid & 63;
    if (ln == 0) {
        #pragma unroll
        for (int e = 0; e < NEXP; ++e) red[wv][e] = p[e];
    }
    __syncthreads();
    if (tid < NEXP) {
        float s = br[tid];
        #pragma unroll
        for (int w = 0; w < 8; ++w) s += red[w][tid];
        LOG[(size_t)t * NEXP + tid] = s;
    }
}

/* --------------- 128x128 MFMA GEMM: C = A * B^T (+bias) --------------- */
__global__ __launch_bounds__(256) void mole_gemm_bt(
    const __bf16* __restrict__ A, int lda,
    const __bf16* __restrict__ B, int ldb,
    float* __restrict__ C, int ldc,
    const float* __restrict__ bias,
    int kChunk, long long cZStride)
{
    __shared__ __align__(16) __bf16 As[128][32];
    __shared__ __align__(16) __bf16 Bs[128][32];

    const int tid = threadIdx.x;
    const int wv  = tid >> 6;
    const int ln  = tid & 63;
    const int wr  = wv >> 1, wc = wv & 1;

    const size_t m0 = (size_t)blockIdx.x * 128;
    const size_t n0 = (size_t)blockIdx.y * 128;
    const int kStart = blockIdx.z * kChunk;
    C += (long long)blockIdx.z * cZStride;

    /* staging: issue i covers rows i*64 + wv*16 + ln/4, colbytes (ln&3)*16 */
    const int srow = (wv << 4) + (ln >> 2);
    const int scol = (ln & 3) << 3;            /* elements */
    const __bf16* gA0 = A + (m0 + srow) * (size_t)lda + kStart + scol;
    const __bf16* gA1 = gA0 + (size_t)64 * lda;
    const __bf16* gB0 = B + (n0 + srow) * (size_t)ldb + kStart + scol;
    const __bf16* gB1 = gB0 + (size_t)64 * ldb;
    __bf16* lA0 = &As[(wv << 4)][0];
    __bf16* lA1 = &As[64 + (wv << 4)][0];
    __bf16* lB0 = &Bs[(wv << 4)][0];
    __bf16* lB1 = &Bs[64 + (wv << 4)][0];

    f32x4 acc[4][4] = {};
    const int fr = ln & 15;
    const int fk = (ln >> 4) << 3;

    const int nSteps = kChunk >> 5;
    for (int ks = 0; ks < nSteps; ++ks) {
        gload_lds16(gA0, lA0);
        gload_lds16(gA1, lA1);
        gload_lds16(gB0, lB0);
        gload_lds16(gB1, lB1);
        gA0 += 32; gA1 += 32; gB0 += 32; gB1 += 32;
        __syncthreads();

        bf16x8 af[4], bfr[4];
        #pragma unroll
        for (int m = 0; m < 4; ++m)
            af[m] = *(const bf16x8*)&As[(wr << 6) + (m << 4) + fr][fk];
        #pragma unroll
        for (int n = 0; n < 4; ++n)
            bfr[n] = *(const bf16x8*)&Bs[(wc << 6) + (n << 4) + fr][fk];
        #pragma unroll
        for (int m = 0; m < 4; ++m)
            #pragma unroll
            for (int n = 0; n < 4; ++n)
                acc[m][n] = __builtin_amdgcn_mfma_f32_16x16x32_bf16(af[m], bfr[n], acc[m][n], 0, 0, 0);
        __syncthreads();
    }

    const int cr = (ln >> 4) << 2;
    const int cc = ln & 15;
    #pragma unroll
    for (int n = 0; n < 4; ++n) {
        const size_t col = n0 + (wc << 6) + (n << 4) + cc;
        const float bv = bias ? bias[col] : 0.0f;
        #pragma unroll
        for (int m = 0; m < 4; ++m) {
            const size_t row = m0 + (wr << 6) + (m << 4) + cr;
            #pragma unroll
            for (int r = 0; r < 4; ++r)
                C[(row + r) * (size_t)ldc + col] = acc[m][n][r] + bv;
        }
    }
}

/* --------- per-token: softmax(LOG) -> w out; g -> XB tail cols --------- */
__global__ __launch_bounds__(64) void mole_softmax_g(
    const float* __restrict__ HP, const float* __restrict__ LOG,
    float* __restrict__ wOut, __bf16* __restrict__ XB)
{
    const int t   = blockIdx.x;
    const int tid = threadIdx.x;     /* 64: one h column each */
    float h = 0.0f;
    #pragma unroll
    for (int sp = 0; sp < 8; ++sp)
        h += HP[((size_t)sp * BT + t) * 128 + 8 + tid];

    float lg[NEXP];
    #pragma unroll
    for (int e = 0; e < NEXP; ++e) lg[e] = LOG[(size_t)t * NEXP + e];
    float mx = lg[0];
    #pragma unroll
    for (int e = 1; e < NEXP; ++e) mx = fmaxf(mx, lg[e]);
    float ex[NEXP], den = 0.0f;
    #pragma unroll
    for (int e = 0; e < NEXP; ++e) { ex[e] = expf(lg[e] - mx); den += ex[e]; }

    const float w_my = ex[tid >> 3] / den;
    XB[(size_t)t * KX + DIN + tid] = (__bf16)(SCALING * w_my * h);
    if (tid < NEXP) wOut[(size_t)t * NEXP + tid] = ex[tid] / den;
}

extern "C" void kernel_launch(void* const* d_in, const int* in_sizes, int n_in,
                              void* d_out, int out_size, void* d_ws, size_t ws_size,
                              hipStream_t stream) {
    const float* x  = (const float*)d_in[0];
    const float* Wf = (const float*)d_in[1];
    const float* bf = (const float*)d_in[2];
    const float* Wr = (const float*)d_in[3];
    const float* br = (const float*)d_in[4];
    const float* A  = (const float*)d_in[5];
    const float* Bm = (const float*)d_in[6];

    float* out0 = (float*)d_out;
    float* wOut = out0 + (size_t)BT * DOUT;

    char* ws = (char*)d_ws;
    __bf16* XB   = (__bf16*)(ws + XB_OFF);
    __bf16* WB   = (__bf16*)(ws + WB_OFF);
    __bf16* ACAT = (__bf16*)(ws + ACAT_OFF);
    float*  HP   = (float*)(ws + HP_OFF);
    float*  LOG  = (float*)(ws + LOG_OFF);

    /* 1. weights -> bf16 layouts */
    mole_prep<<<4864, 256, 0, stream>>>(Wf, Bm, Wr, A, WB, ACAT);
    /* 2. x -> bf16 (stride KX) + exact fp32 router logits */
    mole_convert_x_logits<<<BT, 512, 0, stream>>>(x, Wr, br, XB, LOG);
    /* 3. h-cat = xb @ ACAT^T, 8-way K-split (512 blocks) */
    mole_gemm_bt<<<dim3(64, 1, 8), 256, 0, stream>>>(
        XB, KX, ACAT, DIN, HP, 128, nullptr, DIN / 8, (long long)BT * 128);
    /* 4. softmax + g into XB tail columns; w to output */
    mole_softmax_g<<<BT, 64, 0, stream>>>(HP, LOG, wOut, XB);
    /* 5. out = [xb|g] @ [Wfb|Bcat]^T + bf  (K = 2112) */
    mole_gemm_bt<<<dim3(64, 16, 1), 256, 0, stream>>>(
        XB, KX, WB, KX, out0, DOUT, bf, KX, 0);
}

// Round 2
// 142.420 us; speedup vs baseline: 1.2785x; 1.2785x over previous
//
#include <hip/hip_runtime.h>
#include <hip/hip_bf16.h>

#define BT      8192
#define DIN     2048
#define DOUT    2048
#define NEXP    8
#define RANK    8
#define KX      2112         /* DIN + NEXP*RANK */
#define NT      33           /* KX / 64 */
#define NSPLIT  4            /* K-split for the h-GEMM */
#define SCALING 1.0f         /* ALPHA / RANK = 8/8 */

typedef __bf16 bf16x8 __attribute__((ext_vector_type(8)));
typedef __bf16 bf16x4 __attribute__((ext_vector_type(4)));
typedef float  f32x4  __attribute__((ext_vector_type(4)));

/* ---- ws layout (bytes) ---- */
#define XB_OFF     0
#define XB_BYTES   (BT * KX * 2)
#define WB_OFF     (XB_OFF + XB_BYTES)
#define WB_BYTES   (DOUT * KX * 2)
#define ACAT_OFF   (WB_OFF + WB_BYTES)
#define ACAT_BYTES (128 * DIN * 2)
#define HP_OFF     (ACAT_OFF + ACAT_BYTES)
#define HP_BYTES   (NSPLIT * BT * 128 * 4)
#define LOG_OFF    (HP_OFF + HP_BYTES)

__device__ __forceinline__ void gload_lds16(const void* g, void* l) {
    __builtin_amdgcn_global_load_lds(
        (__attribute__((address_space(1))) void*)(g),
        (__attribute__((address_space(3))) void*)(l),
        16, 0, 0);
}

#define MFMA16(a, b, c) __builtin_amdgcn_mfma_f32_16x16x32_bf16((a), (b), (c), 0, 0, 0)
#define BAR()   __builtin_amdgcn_s_barrier()
#define LGKM0() do { asm volatile("s_waitcnt lgkmcnt(0)" ::: "memory"); \
                     __builtin_amdgcn_sched_barrier(0); } while (0)
#define VM0()   asm volatile("s_waitcnt vmcnt(0)" ::: "memory")

/* ---------------- prep: weights -> bf16 staged layouts ---------------- */
__global__ __launch_bounds__(256) void mole_prep(
    const float* __restrict__ Wf, const float* __restrict__ Bm,
    const float* __restrict__ Wr, const float* __restrict__ A,
    __bf16* __restrict__ WB, __bf16* __restrict__ ACAT)
{
    const int i = blockIdx.x * 256 + threadIdx.x;
    const int R1 = DOUT * (DIN / 4);
    const int R2 = DOUT * 64;
    if (i < R1) {
        const int o = i >> 9, c4 = i & 511;
        float4 v = ((const float4*)Wf)[(size_t)o * 512 + c4];
        bf16x4 b; b[0] = (__bf16)v.x; b[1] = (__bf16)v.y; b[2] = (__bf16)v.z; b[3] = (__bf16)v.w;
        *(bf16x4*)&WB[(size_t)o * KX + (c4 << 2)] = b;
    } else if (i < R1 + R2) {
        const int j = i - R1;
        const int o = j >> 6, c = j & 63;
        const int e = c >> 3, r = c & 7;
        WB[(size_t)o * KX + DIN + c] = (__bf16)Bm[((size_t)e * DOUT + o) * RANK + r];
    } else {
        const int j = i - (R1 + R2);
        const int r = j >> 9, c4 = j & 511;
        float4 v;
        if (r < 8)        v = ((const float4*)Wr)[(size_t)r * 512 + c4];
        else if (r < 72)  v = ((const float4*)A)[(size_t)(r - 8) * 512 + c4];
        else              v = make_float4(0.f, 0.f, 0.f, 0.f);
        bf16x4 b; b[0] = (__bf16)v.x; b[1] = (__bf16)v.y; b[2] = (__bf16)v.z; b[3] = (__bf16)v.w;
        *(bf16x4*)&ACAT[(size_t)r * DIN + (c4 << 2)] = b;
    }
}

/* ------- convert x -> bf16 (stride KX) + exact fp32 router logits ------- */
__global__ __launch_bounds__(512) void mole_convert_x_logits(
    const float* __restrict__ x, const float* __restrict__ Wr,
    const float* __restrict__ br,
    __bf16* __restrict__ XB, float* __restrict__ LOG)
{
    const int t   = blockIdx.x;
    const int tid = threadIdx.x;
    float4 v = ((const float4*)x)[(size_t)t * 512 + tid];
    bf16x4 b; b[0] = (__bf16)v.x; b[1] = (__bf16)v.y; b[2] = (__bf16)v.z; b[3] = (__bf16)v.w;
    *(bf16x4*)&XB[(size_t)t * KX + (tid << 2)] = b;

    float p[NEXP];
    #pragma unroll
    for (int e = 0; e < NEXP; ++e) {
        float4 w4 = ((const float4*)Wr)[e * 512 + tid];
        p[e] = v.x * w4.x + v.y * w4.y + v.z * w4.z + v.w * w4.w;
    }
    #pragma unroll
    for (int e = 0; e < NEXP; ++e)
        #pragma unroll
        for (int off = 32; off > 0; off >>= 1)
            p[e] += __shfl_down(p[e], off);

    __shared__ float red[8][NEXP];
    const int wv = tid >> 6, ln = tid & 63;
    if (ln == 0) {
        #pragma unroll
        for (int e = 0; e < NEXP; ++e) red[wv][e] = p[e];
    }
    __syncthreads();
    if (tid < NEXP) {
        float s = br[tid];
        #pragma unroll
        for (int w = 0; w < 8; ++w) s += red[w][tid];
        LOG[(size_t)t * NEXP + tid] = s;
    }
}

/* ------- 128x128 MFMA GEMM (m97 structure), used for the h-GEMM ------- */
__global__ __launch_bounds__(256) void mole_gemm_bt(
    const __bf16* __restrict__ A, int lda,
    const __bf16* __restrict__ B, int ldb,
    float* __restrict__ C, int ldc,
    int kChunk, long long cZStride)
{
    __shared__ __align__(16) __bf16 As[128][32];
    __shared__ __align__(16) __bf16 Bs[128][32];

    const int tid = threadIdx.x;
    const int wv  = tid >> 6;
    const int ln  = tid & 63;
    const int wr  = wv >> 1, wc = wv & 1;

    const size_t m0 = (size_t)blockIdx.x * 128;
    const size_t n0 = (size_t)blockIdx.y * 128;
    const int kStart = blockIdx.z * kChunk;
    C += (long long)blockIdx.z * cZStride;

    const int srow = (wv << 4) + (ln >> 2);
    const int scol = (ln & 3) << 3;
    const __bf16* gA0 = A + (m0 + srow) * (size_t)lda + kStart + scol;
    const __bf16* gA1 = gA0 + (size_t)64 * lda;
    const __bf16* gB0 = B + (n0 + srow) * (size_t)ldb + kStart + scol;
    const __bf16* gB1 = gB0 + (size_t)64 * ldb;
    __bf16* lA0 = &As[(wv << 4)][0];
    __bf16* lA1 = &As[64 + (wv << 4)][0];
    __bf16* lB0 = &Bs[(wv << 4)][0];
    __bf16* lB1 = &Bs[64 + (wv << 4)][0];

    f32x4 acc[4][4] = {};
    const int fr = ln & 15;
    const int fk = (ln >> 4) << 3;

    const int nSteps = kChunk >> 5;
    for (int ks = 0; ks < nSteps; ++ks) {
        gload_lds16(gA0, lA0);
        gload_lds16(gA1, lA1);
        gload_lds16(gB0, lB0);
        gload_lds16(gB1, lB1);
        gA0 += 32; gA1 += 32; gB0 += 32; gB1 += 32;
        __syncthreads();

        bf16x8 af[4], bfr[4];
        #pragma unroll
        for (int m = 0; m < 4; ++m)
            af[m] = *(const bf16x8*)&As[(wr << 6) + (m << 4) + fr][fk];
        #pragma unroll
        for (int n = 0; n < 4; ++n)
            bfr[n] = *(const bf16x8*)&Bs[(wc << 6) + (n << 4) + fr][fk];
        #pragma unroll
        for (int m = 0; m < 4; ++m)
            #pragma unroll
            for (int n = 0; n < 4; ++n)
                acc[m][n] = MFMA16(af[m], bfr[n], acc[m][n]);
        __syncthreads();
    }

    const int cr = (ln >> 4) << 2;
    const int cc = ln & 15;
    #pragma unroll
    for (int n = 0; n < 4; ++n) {
        const size_t col = n0 + (wc << 6) + (n << 4) + cc;
        #pragma unroll
        for (int m = 0; m < 4; ++m) {
            const size_t row = m0 + (wr << 6) + (m << 4) + cr;
            #pragma unroll
            for (int r = 0; r < 4; ++r)
                C[(row + r) * (size_t)ldc + col] = acc[m][n][r];
        }
    }
}

/* --------- per-token: softmax(LOG) -> w out; g -> XB tail cols --------- */
__global__ __launch_bounds__(64) void mole_softmax_g(
    const float* __restrict__ HP, const float* __restrict__ LOG,
    float* __restrict__ wOut, __bf16* __restrict__ XB)
{
    const int t   = blockIdx.x;
    const int tid = threadIdx.x;
    float h = 0.0f;
    #pragma unroll
    for (int sp = 0; sp < NSPLIT; ++sp)
        h += HP[((size_t)sp * BT + t) * 128 + 8 + tid];

    float lg[NEXP];
    #pragma unroll
    for (int e = 0; e < NEXP; ++e) lg[e] = LOG[(size_t)t * NEXP + e];
    float mx = lg[0];
    #pragma unroll
    for (int e = 1; e < NEXP; ++e) mx = fmaxf(mx, lg[e]);
    float ex[NEXP], den = 0.0f;
    #pragma unroll
    for (int e = 0; e < NEXP; ++e) { ex[e] = expf(lg[e] - mx); den += ex[e]; }

    const float w_my = ex[tid >> 3] / den;
    XB[(size_t)t * KX + DIN + tid] = (__bf16)(SCALING * w_my * h);
    if (tid < NEXP) wOut[(size_t)t * NEXP + tid] = ex[tid] / den;
}

/* ================= main 256x256 8-phase GEMM (T1-T5) =================
   C[8192,2048] = XB[8192,KX] * WB[2048,KX]^T + bias
   8 waves (2M x 4N), per-wave 128x64 out, BK=64, 4 phases/K-tile.
   LDS 128KB: [buf(2)][op(2)][row(256)][slot(8)x16B], slot ^= row&7 swizzle
   applied by pre-swizzling the GLOBAL source (gload_lds dest stays linear). */
__global__ __launch_bounds__(512, 2) void mole_gemm256(
    const __bf16* __restrict__ XBp, const __bf16* __restrict__ WBp,
    float* __restrict__ C, const float* __restrict__ bias)
{
    __shared__ __align__(16) char smem[131072];

    const int tid = threadIdx.x;
    const int wv  = tid >> 6, l = tid & 63;
    const int wm  = wv >> 2, wn = wv & 3;
    const int bid = blockIdx.x;
    const int tn  = bid & 7, tm = bid >> 3;      /* XCD x owns B-panel tn=x */
    const size_t m0 = (size_t)tm * 256, n0 = (size_t)tn * 256;

    /* staging: waves 0-3 stage A (XB rows), 4-7 stage B (WB rows).
       instr j covers 8 rows x 128B; lane l -> row +(l>>3), slot (l&7)^(l>>3) */
    const int op = wv >> 2;
    const int segBase = (wv & 3) << 3;           /* 8 segments per wave */
    const __bf16* gsrc = (op == 0)
        ? XBp + (m0 + (size_t)(segBase << 3)) * KX
        : WBp + (n0 + (size_t)(segBase << 3)) * KX;
    gsrc += (size_t)(l >> 3) * KX + (((l & 7) ^ (l >> 3)) << 3);
    char* ldsStage0 = smem + op * 32768 + segBase * 1024;

    /* fragment addressing: row r -> phys slot (kk*4+fq)^(l&7) (r&7 == l&7) */
    const int fr = l & 15, fq = l >> 4;
    const int spb0 = ((fq)     ^ (l & 7)) << 4;
    const int spb1 = ((4 + fq) ^ (l & 7)) << 4;
    const char* aBase = smem + (wm * 128 + fr) * 128;
    const char* bBase = smem + 32768 + (wn * 64 + fr) * 128;

    f32x4 acc[8][4] = {};
    bf16x8 fa[4][2], fb[4][2];

    /* prologue: stage tile 0 -> buf 0, full drain */
    #pragma unroll
    for (int j = 0; j < 8; ++j)
        gload_lds16(gsrc + (size_t)j * 8 * KX, ldsStage0 + j * 1024);
    VM0();
    BAR();

    for (int t = 0; t < NT; ++t) {
        const int p = t & 1;
        const char* aB = aBase + p * 65536;
        const char* bB = bBase + p * 65536;
        const bool st = (t + 1 < NT);
        const __bf16* gs = gsrc + (size_t)(t + 1) * 64;
        char* ldst = ldsStage0 + (p ^ 1) * 65536;

        /* ---- phase 0: quadrant (mf 0-3, nf 0-1); stage j0-3 ---- */
        #pragma unroll
        for (int mf = 0; mf < 4; ++mf) {
            fa[mf][0] = *(const bf16x8*)(aB + mf * 2048 + spb0);
            fa[mf][1] = *(const bf16x8*)(aB + mf * 2048 + spb1);
        }
        #pragma unroll
        for (int nf = 0; nf < 2; ++nf) {
            fb[nf][0] = *(const bf16x8*)(bB + nf * 2048 + spb0);
            fb[nf][1] = *(const bf16x8*)(bB + nf * 2048 + spb1);
        }
        if (st) {
            #pragma unroll
            for (int j = 0; j < 4; ++j)
                gload_lds16(gs + (size_t)j * 8 * KX, ldst + j * 1024);
        }
        BAR();
        LGKM0();
        __builtin_amdgcn_s_setprio(1);
        #pragma unroll
        for (int kk = 0; kk < 2; ++kk)
            #pragma unroll
            for (int mf = 0; mf < 4; ++mf)
                #pragma unroll
                for (int nf = 0; nf < 2; ++nf)
                    acc[mf][nf] = MFMA16(fa[mf][kk], fb[nf][kk], acc[mf][nf]);
        __builtin_amdgcn_s_setprio(0);
        BAR();

        /* ---- phase 1: quadrant (mf 0-3, nf 2-3); stage j4-7 ---- */
        #pragma unroll
        for (int nf = 2; nf < 4; ++nf) {
            fb[nf][0] = *(const bf16x8*)(bB + nf * 2048 + spb0);
            fb[nf][1] = *(const bf16x8*)(bB + nf * 2048 + spb1);
        }
        if (st) {
            #pragma unroll
            for (int j = 4; j < 8; ++j)
                gload_lds16(gs + (size_t)j * 8 * KX, ldst + j * 1024);
        }
        BAR();
        LGKM0();
        __builtin_amdgcn_s_setprio(1);
        #pragma unroll
        for (int kk = 0; kk < 2; ++kk)
            #pragma unroll
            for (int mf = 0; mf < 4; ++mf)
                #pragma unroll
                for (int nf = 2; nf < 4; ++nf)
                    acc[mf][nf] = MFMA16(fa[mf][kk], fb[nf][kk], acc[mf][nf]);
        __builtin_amdgcn_s_setprio(0);
        BAR();

        /* ---- phase 2: quadrant (mf 4-7, nf 0-1) ---- */
        #pragma unroll
        for (int mf = 0; mf < 4; ++mf) {
            fa[mf][0] = *(const bf16x8*)(aB + (4 + mf) * 2048 + spb0);
            fa[mf][1] = *(const bf16x8*)(aB + (4 + mf) * 2048 + spb1);
        }
        BAR();
        LGKM0();
        __builtin_amdgcn_s_setprio(1);
        #pragma unroll
        for (int kk = 0; kk < 2; ++kk)
            #pragma unroll
            for (int mf = 0; mf < 4; ++mf)
                #pragma unroll
                for (int nf = 0; nf < 2; ++nf)
                    acc[4 + mf][nf] = MFMA16(fa[mf][kk], fb[nf][kk], acc[4 + mf][nf]);
        __builtin_amdgcn_s_setprio(0);
        BAR();

        /* ---- phase 3: quadrant (mf 4-7, nf 2-3); drain next tile ---- */
        __builtin_amdgcn_s_setprio(1);
        #pragma unroll
        for (int kk = 0; kk < 2; ++kk)
            #pragma unroll
            for (int mf = 0; mf < 4; ++mf)
                #pragma unroll
                for (int nf = 2; nf < 4; ++nf)
                    acc[4 + mf][nf] = MFMA16(fa[mf][kk], fb[nf][kk], acc[4 + mf][nf]);
        __builtin_amdgcn_s_setprio(0);
        if (st) VM0();          /* all of tile t+1 issued >=2 phases ago */
        BAR();
    }

    /* epilogue: C = acc + bias */
    const size_t crow = m0 + wm * 128 + fq * 4;
    const size_t ccol = n0 + wn * 64 + fr;
    #pragma unroll
    for (int nf = 0; nf < 4; ++nf) {
        const float bv = bias[ccol + nf * 16];
        #pragma unroll
        for (int mf = 0; mf < 8; ++mf) {
            float* cp = C + (crow + (size_t)mf * 16) * DOUT + ccol + nf * 16;
            #pragma unroll
            for (int i = 0; i < 4; ++i)
                cp[(size_t)i * DOUT] = acc[mf][nf][i] + bv;
        }
    }
}

extern "C" void kernel_launch(void* const* d_in, const int* in_sizes, int n_in,
                              void* d_out, int out_size, void* d_ws, size_t ws_size,
                              hipStream_t stream) {
    const float* x  = (const float*)d_in[0];
    const float* Wf = (const float*)d_in[1];
    const float* bf = (const float*)d_in[2];
    const float* Wr = (const float*)d_in[3];
    const float* br = (const float*)d_in[4];
    const float* A  = (const float*)d_in[5];
    const float* Bm = (const float*)d_in[6];

    float* out0 = (float*)d_out;
    float* wOut = out0 + (size_t)BT * DOUT;

    char* ws = (char*)d_ws;
    __bf16* XB   = (__bf16*)(ws + XB_OFF);
    __bf16* WB   = (__bf16*)(ws + WB_OFF);
    __bf16* ACAT = (__bf16*)(ws + ACAT_OFF);
    float*  HP   = (float*)(ws + HP_OFF);
    float*  LOG  = (float*)(ws + LOG_OFF);

    /* 1. weights -> bf16 layouts */
    mole_prep<<<4864, 256, 0, stream>>>(Wf, Bm, Wr, A, WB, ACAT);
    /* 2. x -> bf16 (stride KX) + exact fp32 router logits */
    mole_convert_x_logits<<<BT, 512, 0, stream>>>(x, Wr, br, XB, LOG);
    /* 3. h-cat = xb @ ACAT^T, 4-way K-split (256 blocks) */
    mole_gemm_bt<<<dim3(64, 1, NSPLIT), 256, 0, stream>>>(
        XB, KX, ACAT, DIN, HP, 128, DIN / NSPLIT, (long long)BT * 128);
    /* 4. softmax + g into XB tail columns; w to output */
    mole_softmax_g<<<BT, 64, 0, stream>>>(HP, LOG, wOut, XB);
    /* 5. out = [xb|g] @ [Wfb|Bcat]^T + bf  (K = 2112, 256^2 8-phase) */
    mole_gemm256<<<256, 512, 0, stream>>>(XB, WB, out0, bf);
}

// Round 3
// 137.873 us; speedup vs baseline: 1.3207x; 1.0330x over previous
//
#include <hip/hip_runtime.h>
#include <hip/hip_bf16.h>

#define BT      8192
#define DIN     2048
#define DOUT    2048
#define NEXP    8
#define RANK    8
#define KX      2112         /* DIN + NEXP*RANK */
#define NSUB    66           /* KX / 32 K-subtiles */
#define NSPLIT  4            /* K-split for the h-GEMM */
#define SCALING 1.0f         /* ALPHA / RANK = 8/8 */

typedef __bf16 bf16x8 __attribute__((ext_vector_type(8)));
typedef __bf16 bf16x4 __attribute__((ext_vector_type(4)));
typedef float  f32x4  __attribute__((ext_vector_type(4)));

/* ---- ws layout (bytes) ---- */
#define XB_OFF     0
#define XB_BYTES   (BT * KX * 2)
#define WB_OFF     (XB_OFF + XB_BYTES)
#define WB_BYTES   (DOUT * KX * 2)
#define ACAT_OFF   (WB_OFF + WB_BYTES)
#define ACAT_BYTES (128 * DIN * 2)
#define HP_OFF     (ACAT_OFF + ACAT_BYTES)
#define HP_BYTES   (NSPLIT * BT * 128 * 4)
#define LOG_OFF    (HP_OFF + HP_BYTES)

__device__ __forceinline__ void gload_lds16(const void* g, void* l) {
    __builtin_amdgcn_global_load_lds(
        (__attribute__((address_space(1))) void*)(g),
        (__attribute__((address_space(3))) void*)(l),
        16, 0, 0);
}

#define MFMA16(a, b, c) __builtin_amdgcn_mfma_f32_16x16x32_bf16((a), (b), (c), 0, 0, 0)

/* ---------------- prep: weights -> bf16 staged layouts ---------------- */
__global__ __launch_bounds__(256) void mole_prep(
    const float* __restrict__ Wf, const float* __restrict__ Bm,
    const float* __restrict__ Wr, const float* __restrict__ A,
    __bf16* __restrict__ WB, __bf16* __restrict__ ACAT)
{
    const int i = blockIdx.x * 256 + threadIdx.x;
    const int R1 = DOUT * (DIN / 4);
    const int R2 = DOUT * 64;
    if (i < R1) {
        const int o = i >> 9, c4 = i & 511;
        float4 v = ((const float4*)Wf)[(size_t)o * 512 + c4];
        bf16x4 b; b[0] = (__bf16)v.x; b[1] = (__bf16)v.y; b[2] = (__bf16)v.z; b[3] = (__bf16)v.w;
        *(bf16x4*)&WB[(size_t)o * KX + (c4 << 2)] = b;
    } else if (i < R1 + R2) {
        const int j = i - R1;
        const int o = j >> 6, c = j & 63;
        const int e = c >> 3, r = c & 7;
        WB[(size_t)o * KX + DIN + c] = (__bf16)Bm[((size_t)e * DOUT + o) * RANK + r];
    } else {
        const int j = i - (R1 + R2);
        const int r = j >> 9, c4 = j & 511;
        float4 v;
        if (r < 8)        v = ((const float4*)Wr)[(size_t)r * 512 + c4];
        else if (r < 72)  v = ((const float4*)A)[(size_t)(r - 8) * 512 + c4];
        else              v = make_float4(0.f, 0.f, 0.f, 0.f);
        bf16x4 b; b[0] = (__bf16)v.x; b[1] = (__bf16)v.y; b[2] = (__bf16)v.z; b[3] = (__bf16)v.w;
        *(bf16x4*)&ACAT[(size_t)r * DIN + (c4 << 2)] = b;
    }
}

/* ------- convert x -> bf16 (stride KX) + exact fp32 router logits ------- */
__global__ __launch_bounds__(512) void mole_convert_x_logits(
    const float* __restrict__ x, const float* __restrict__ Wr,
    const float* __restrict__ br,
    __bf16* __restrict__ XB, float* __restrict__ LOG)
{
    const int t   = blockIdx.x;
    const int tid = threadIdx.x;
    float4 v = ((const float4*)x)[(size_t)t * 512 + tid];
    bf16x4 b; b[0] = (__bf16)v.x; b[1] = (__bf16)v.y; b[2] = (__bf16)v.z; b[3] = (__bf16)v.w;
    *(bf16x4*)&XB[(size_t)t * KX + (tid << 2)] = b;

    float p[NEXP];
    #pragma unroll
    for (int e = 0; e < NEXP; ++e) {
        float4 w4 = ((const float4*)Wr)[e * 512 + tid];
        p[e] = v.x * w4.x + v.y * w4.y + v.z * w4.z + v.w * w4.w;
    }
    #pragma unroll
    for (int e = 0; e < NEXP; ++e)
        #pragma unroll
        for (int off = 32; off > 0; off >>= 1)
            p[e] += __shfl_down(p[e], off);

    __shared__ float red[8][NEXP];
    const int wv = tid >> 6, ln = tid & 63;
    if (ln == 0) {
        #pragma unroll
        for (int e = 0; e < NEXP; ++e) red[wv][e] = p[e];
    }
    __syncthreads();
    if (tid < NEXP) {
        float s = br[tid];
        #pragma unroll
        for (int w = 0; w < 8; ++w) s += red[w][tid];
        LOG[(size_t)t * NEXP + tid] = s;
    }
}

/* ------- 128x128 MFMA GEMM (m97 structure), used for the h-GEMM ------- */
__global__ __launch_bounds__(256) void mole_gemm_bt(
    const __bf16* __restrict__ A, int lda,
    const __bf16* __restrict__ B, int ldb,
    float* __restrict__ C, int ldc,
    int kChunk, long long cZStride)
{
    __shared__ __align__(16) __bf16 As[128][32];
    __shared__ __align__(16) __bf16 Bs[128][32];

    const int tid = threadIdx.x;
    const int wv  = tid >> 6;
    const int ln  = tid & 63;
    const int wr  = wv >> 1, wc = wv & 1;

    const size_t m0 = (size_t)blockIdx.x * 128;
    const size_t n0 = (size_t)blockIdx.y * 128;
    const int kStart = blockIdx.z * kChunk;
    C += (long long)blockIdx.z * cZStride;

    const int srow = (wv << 4) + (ln >> 2);
    const int scol = (ln & 3) << 3;
    const __bf16* gA0 = A + (m0 + srow) * (size_t)lda + kStart + scol;
    const __bf16* gA1 = gA0 + (size_t)64 * lda;
    const __bf16* gB0 = B + (n0 + srow) * (size_t)ldb + kStart + scol;
    const __bf16* gB1 = gB0 + (size_t)64 * ldb;
    __bf16* lA0 = &As[(wv << 4)][0];
    __bf16* lA1 = &As[64 + (wv << 4)][0];
    __bf16* lB0 = &Bs[(wv << 4)][0];
    __bf16* lB1 = &Bs[64 + (wv << 4)][0];

    f32x4 acc[4][4] = {};
    const int fr = ln & 15;
    const int fk = (ln >> 4) << 3;

    const int nSteps = kChunk >> 5;
    for (int ks = 0; ks < nSteps; ++ks) {
        gload_lds16(gA0, lA0);
        gload_lds16(gA1, lA1);
        gload_lds16(gB0, lB0);
        gload_lds16(gB1, lB1);
        gA0 += 32; gA1 += 32; gB0 += 32; gB1 += 32;
        __syncthreads();

        bf16x8 af[4], bfr[4];
        #pragma unroll
        for (int m = 0; m < 4; ++m)
            af[m] = *(const bf16x8*)&As[(wr << 6) + (m << 4) + fr][fk];
        #pragma unroll
        for (int n = 0; n < 4; ++n)
            bfr[n] = *(const bf16x8*)&Bs[(wc << 6) + (n << 4) + fr][fk];
        #pragma unroll
        for (int m = 0; m < 4; ++m)
            #pragma unroll
            for (int n = 0; n < 4; ++n)
                acc[m][n] = MFMA16(af[m], bfr[n], acc[m][n]);
        __syncthreads();
    }

    const int cr = (ln >> 4) << 2;
    const int cc = ln & 15;
    #pragma unroll
    for (int n = 0; n < 4; ++n) {
        const size_t col = n0 + (wc << 6) + (n << 4) + cc;
        #pragma unroll
        for (int m = 0; m < 4; ++m) {
            const size_t row = m0 + (wr << 6) + (m << 4) + cr;
            #pragma unroll
            for (int r = 0; r < 4; ++r)
                C[(row + r) * (size_t)ldc + col] = acc[m][n][r];
        }
    }
}

/* --------- per-token: softmax(LOG) -> w out; g -> XB tail cols --------- */
__global__ __launch_bounds__(64) void mole_softmax_g(
    const float* __restrict__ HP, const float* __restrict__ LOG,
    float* __restrict__ wOut, __bf16* __restrict__ XB)
{
    const int t   = blockIdx.x;
    const int tid = threadIdx.x;
    float h = 0.0f;
    #pragma unroll
    for (int sp = 0; sp < NSPLIT; ++sp)
        h += HP[((size_t)sp * BT + t) * 128 + 8 + tid];

    float lg[NEXP];
    #pragma unroll
    for (int e = 0; e < NEXP; ++e) lg[e] = LOG[(size_t)t * NEXP + e];
    float mx = lg[0];
    #pragma unroll
    for (int e = 1; e < NEXP; ++e) mx = fmaxf(mx, lg[e]);
    float ex[NEXP], den = 0.0f;
    #pragma unroll
    for (int e = 0; e < NEXP; ++e) { ex[e] = expf(lg[e] - mx); den += ex[e]; }

    const float w_my = ex[tid >> 3] / den;
    XB[(size_t)t * KX + DIN + tid] = (__bf16)(SCALING * w_my * h);
    if (tid < NEXP) wOut[(size_t)t * NEXP + tid] = ex[tid] / den;
}

/* ============ main 256x256 GEMM: ring-4 BK=32, counted vmcnt ============
   C[8192,2048] = XB[8192,KX] * WB[2048,KX]^T + bias
   8 waves (2M x 4N), per-wave 128x64 out. LDS = 4 ring slots x 32 KB
   ([A 256x32 | B 256x32] bf16, 64 B/row, slot16B ^= row&3 swizzle via
   pre-swizzled global source; gload_lds dest linear).
   Per step: vmcnt(8) -> barrier -> 12 ds_read_b128 + 4 gload_lds(s+3)
   -> lgkmcnt(0) -> 32 MFMA. Loads in flight 3 steps; never vmcnt(0)
   in main loop (T4). */
__global__ __launch_bounds__(512, 1) void mole_gemm256(
    const __bf16* __restrict__ XBp, const __bf16* __restrict__ WBp,
    float* __restrict__ C, const float* __restrict__ bias)
{
    __shared__ __align__(16) char smem[131072];

    const int tid = threadIdx.x;
    const int wv  = tid >> 6, l = tid & 63;
    const int wm  = wv >> 2, wn = wv & 3;
    const int bid = blockIdx.x;
    /* T1: XCD x (= bid&7) owns tm in [4x,4x+4) x all tn: 4 A-panels + 8
       B-panels = 13 MB L2-fill per XCD (vs 35 MB with tn=bid&7) */
    const int xcd = bid & 7, ib = bid >> 3;
    const int tm = xcd * 4 + (ib & 3), tn = ib >> 2;
    const size_t m0 = (size_t)tm * 256, n0 = (size_t)tn * 256;

    /* staging: waves 0-3 stage A rows, waves 4-7 stage B rows.
       Per sub-tile, wave covers 64 rows (4 instrs x 16 rows). Lane l ->
       row +(l>>2), phys slot l&3 <- logical col ((l&3)^((l>>2)&3)). */
    const int op = wv >> 2, ww = wv & 3;
    const __bf16* gstage = (op == 0 ? XBp + (m0 + ww * 64) * KX
                                    : WBp + (n0 + ww * 64) * KX)
                         + (size_t)(l >> 2) * KX + (((l & 3) ^ ((l >> 2) & 3)) << 3);
    const int stageBase = op * 16384 + ww * 4096;

    /* fragment read: row R, logical k-slot fq -> phys slot fq^(R&3) */
    const int fr = l & 15, fq = l >> 4;
    const int swz = (fq ^ (fr & 3)) << 4;
    const int aByte = (wm * 128 + fr) * 64 + swz;
    const int bByte = 16384 + (wn * 64 + fr) * 64 + swz;

    f32x4 acc[8][4] = {};

    /* prologue: stage sub-tiles 0,1,2 (12 loads/thread) */
    #pragma unroll
    for (int s = 0; s < 3; ++s) {
        char* dst = smem + s * 32768 + stageBase;
        const __bf16* g = gstage + (size_t)s * 32;
        #pragma unroll
        for (int j = 0; j < 4; ++j)
            gload_lds16(g + (size_t)j * 16 * KX, dst + j * 1024);
    }

#define STEP(S, VMN, ST)                                                      \
    {                                                                         \
        asm volatile("s_waitcnt vmcnt(" #VMN ")" ::: "memory");               \
        __builtin_amdgcn_s_barrier();                                         \
        const char* slot = smem + ((S) & 3) * 32768;                          \
        bf16x8 fa[8], fb[4];                                                  \
        _Pragma("unroll")                                                     \
        for (int mf = 0; mf < 8; ++mf)                                        \
            fa[mf] = *(const bf16x8*)(slot + aByte + mf * 1024);              \
        _Pragma("unroll")                                                     \
        for (int nf = 0; nf < 4; ++nf)                                        \
            fb[nf] = *(const bf16x8*)(slot + bByte + nf * 1024);              \
        if (ST) {                                                             \
            char* dst = smem + (((S) + 3) & 3) * 32768 + stageBase;           \
            const __bf16* g = gstage + (size_t)((S) + 3) * 32;                \
            _Pragma("unroll")                                                 \
            for (int j = 0; j < 4; ++j)                                       \
                gload_lds16(g + (size_t)j * 16 * KX, dst + j * 1024);         \
        }                                                                     \
        asm volatile("s_waitcnt lgkmcnt(0)" ::: "memory");                    \
        __builtin_amdgcn_sched_barrier(0);                                    \
        __builtin_amdgcn_s_setprio(1);                                        \
        _Pragma("unroll")                                                     \
        for (int mf = 0; mf < 8; ++mf)                                        \
            _Pragma("unroll")                                                 \
            for (int nf = 0; nf < 4; ++nf)                                    \
                acc[mf][nf] = MFMA16(fa[mf], fb[nf], acc[mf][nf]);            \
        __builtin_amdgcn_s_setprio(0);                                        \
    }

    #pragma unroll 1
    for (int s = 0; s < NSUB - 3; ++s)
        STEP(s, 8, true);
    STEP(NSUB - 3, 8, false);
    STEP(NSUB - 2, 4, false);
    STEP(NSUB - 1, 0, false);
#undef STEP

    /* epilogue: C = acc + bias */
    const size_t crow = m0 + wm * 128 + fq * 4;
    const size_t ccol = n0 + wn * 64 + fr;
    #pragma unroll
    for (int nf = 0; nf < 4; ++nf) {
        const float bv = bias[ccol + nf * 16];
        #pragma unroll
        for (int mf = 0; mf < 8; ++mf) {
            float* cp = C + (crow + (size_t)mf * 16) * DOUT + ccol + nf * 16;
            #pragma unroll
            for (int i = 0; i < 4; ++i)
                cp[(size_t)i * DOUT] = acc[mf][nf][i] + bv;
        }
    }
}

extern "C" void kernel_launch(void* const* d_in, const int* in_sizes, int n_in,
                              void* d_out, int out_size, void* d_ws, size_t ws_size,
                              hipStream_t stream) {
    const float* x  = (const float*)d_in[0];
    const float* Wf = (const float*)d_in[1];
    const float* bf = (const float*)d_in[2];
    const float* Wr = (const float*)d_in[3];
    const float* br = (const float*)d_in[4];
    const float* A  = (const float*)d_in[5];
    const float* Bm = (const float*)d_in[6];

    float* out0 = (float*)d_out;
    float* wOut = out0 + (size_t)BT * DOUT;

    char* ws = (char*)d_ws;
    __bf16* XB   = (__bf16*)(ws + XB_OFF);
    __bf16* WB   = (__bf16*)(ws + WB_OFF);
    __bf16* ACAT = (__bf16*)(ws + ACAT_OFF);
    float*  HP   = (float*)(ws + HP_OFF);
    float*  LOG  = (float*)(ws + LOG_OFF);

    /* 1. weights -> bf16 layouts */
    mole_prep<<<4864, 256, 0, stream>>>(Wf, Bm, Wr, A, WB, ACAT);
    /* 2. x -> bf16 (stride KX) + exact fp32 router logits */
    mole_convert_x_logits<<<BT, 512, 0, stream>>>(x, Wr, br, XB, LOG);
    /* 3. h-cat = xb @ ACAT^T, 4-way K-split (256 blocks) */
    mole_gemm_bt<<<dim3(64, 1, NSPLIT), 256, 0, stream>>>(
        XB, KX, ACAT, DIN, HP, 128, DIN / NSPLIT, (long long)BT * 128);
    /* 4. softmax + g into XB tail columns; w to output */
    mole_softmax_g<<<BT, 64, 0, stream>>>(HP, LOG, wOut, XB);
    /* 5. out = [xb|g] @ [Wfb|Bcat]^T + bf  (K = 2112, ring-4 counted-vmcnt) */
    mole_gemm256<<<256, 512, 0, stream>>>(XB, WB, out0, bf);
}

// Round 4
// 136.745 us; speedup vs baseline: 1.3316x; 1.0083x over previous
//
#include <hip/hip_runtime.h>
#include <hip/hip_bf16.h>

#define BT      8192
#define DIN     2048
#define DOUT    2048
#define NEXP    8
#define RANK    8
#define KX      2112         /* DIN + NEXP*RANK */
#define NSUB    66           /* KX / 32 K-subtiles */
#define NSPLIT  4            /* K-split for the h-GEMM */
#define SCALING 1.0f         /* ALPHA / RANK = 8/8 */

typedef __bf16 bf16x8 __attribute__((ext_vector_type(8)));
typedef __bf16 bf16x4 __attribute__((ext_vector_type(4)));
typedef float  f32x4  __attribute__((ext_vector_type(4)));

/* ---- ws layout (bytes) ---- */
#define XB_OFF     0
#define XB_BYTES   (BT * KX * 2)
#define WB_OFF     (XB_OFF + XB_BYTES)
#define WB_BYTES   (DOUT * KX * 2)
#define ACAT_OFF   (WB_OFF + WB_BYTES)
#define ACAT_BYTES (128 * DIN * 2)
#define HP_OFF     (ACAT_OFF + ACAT_BYTES)
#define HP_BYTES   (NSPLIT * BT * 128 * 4)
#define LOG_OFF    (HP_OFF + HP_BYTES)

__device__ __forceinline__ void gload_lds16(const void* g, void* l) {
    __builtin_amdgcn_global_load_lds(
        (__attribute__((address_space(1))) void*)(g),
        (__attribute__((address_space(3))) void*)(l),
        16, 0, 0);
}

#define MFMA16(a, b, c) __builtin_amdgcn_mfma_f32_16x16x32_bf16((a), (b), (c), 0, 0, 0)

/* ---------------- prep: weights -> bf16 staged layouts ---------------- */
__global__ __launch_bounds__(256) void mole_prep(
    const float* __restrict__ Wf, const float* __restrict__ Bm,
    const float* __restrict__ Wr, const float* __restrict__ A,
    __bf16* __restrict__ WB, __bf16* __restrict__ ACAT)
{
    const int i = blockIdx.x * 256 + threadIdx.x;
    const int R1 = DOUT * (DIN / 4);
    const int R2 = DOUT * 64;
    if (i < R1) {
        const int o = i >> 9, c4 = i & 511;
        float4 v = ((const float4*)Wf)[(size_t)o * 512 + c4];
        bf16x4 b; b[0] = (__bf16)v.x; b[1] = (__bf16)v.y; b[2] = (__bf16)v.z; b[3] = (__bf16)v.w;
        *(bf16x4*)&WB[(size_t)o * KX + (c4 << 2)] = b;
    } else if (i < R1 + R2) {
        const int j = i - R1;
        const int o = j >> 6, c = j & 63;
        const int e = c >> 3, r = c & 7;
        WB[(size_t)o * KX + DIN + c] = (__bf16)Bm[((size_t)e * DOUT + o) * RANK + r];
    } else {
        const int j = i - (R1 + R2);
        const int r = j >> 9, c4 = j & 511;
        float4 v;
        if (r < 8)        v = ((const float4*)Wr)[(size_t)r * 512 + c4];
        else if (r < 72)  v = ((const float4*)A)[(size_t)(r - 8) * 512 + c4];
        else              v = make_float4(0.f, 0.f, 0.f, 0.f);
        bf16x4 b; b[0] = (__bf16)v.x; b[1] = (__bf16)v.y; b[2] = (__bf16)v.z; b[3] = (__bf16)v.w;
        *(bf16x4*)&ACAT[(size_t)r * DIN + (c4 << 2)] = b;
    }
}

/* ------- convert x -> bf16 (stride KX) + exact fp32 router logits ------- */
__global__ __launch_bounds__(512) void mole_convert_x_logits(
    const float* __restrict__ x, const float* __restrict__ Wr,
    const float* __restrict__ br,
    __bf16* __restrict__ XB, float* __restrict__ LOG)
{
    const int t   = blockIdx.x;
    const int tid = threadIdx.x;
    float4 v = ((const float4*)x)[(size_t)t * 512 + tid];
    bf16x4 b; b[0] = (__bf16)v.x; b[1] = (__bf16)v.y; b[2] = (__bf16)v.z; b[3] = (__bf16)v.w;
    *(bf16x4*)&XB[(size_t)t * KX + (tid << 2)] = b;

    float p[NEXP];
    #pragma unroll
    for (int e = 0; e < NEXP; ++e) {
        float4 w4 = ((const float4*)Wr)[e * 512 + tid];
        p[e] = v.x * w4.x + v.y * w4.y + v.z * w4.z + v.w * w4.w;
    }
    #pragma unroll
    for (int e = 0; e < NEXP; ++e)
        #pragma unroll
        for (int off = 32; off > 0; off >>= 1)
            p[e] += __shfl_down(p[e], off);

    __shared__ float red[8][NEXP];
    const int wv = tid >> 6, ln = tid & 63;
    if (ln == 0) {
        #pragma unroll
        for (int e = 0; e < NEXP; ++e) red[wv][e] = p[e];
    }
    __syncthreads();
    if (tid < NEXP) {
        float s = br[tid];
        #pragma unroll
        for (int w = 0; w < 8; ++w) s += red[w][tid];
        LOG[(size_t)t * NEXP + tid] = s;
    }
}

/* ------- 128x128 MFMA GEMM (m97 structure), used for the h-GEMM ------- */
__global__ __launch_bounds__(256) void mole_gemm_bt(
    const __bf16* __restrict__ A, int lda,
    const __bf16* __restrict__ B, int ldb,
    float* __restrict__ C, int ldc,
    int kChunk, long long cZStride)
{
    __shared__ __align__(16) __bf16 As[128][32];
    __shared__ __align__(16) __bf16 Bs[128][32];

    const int tid = threadIdx.x;
    const int wv  = tid >> 6;
    const int ln  = tid & 63;
    const int wr  = wv >> 1, wc = wv & 1;

    const size_t m0 = (size_t)blockIdx.x * 128;
    const size_t n0 = (size_t)blockIdx.y * 128;
    const int kStart = blockIdx.z * kChunk;
    C += (long long)blockIdx.z * cZStride;

    const int srow = (wv << 4) + (ln >> 2);
    const int scol = (ln & 3) << 3;
    const __bf16* gA0 = A + (m0 + srow) * (size_t)lda + kStart + scol;
    const __bf16* gA1 = gA0 + (size_t)64 * lda;
    const __bf16* gB0 = B + (n0 + srow) * (size_t)ldb + kStart + scol;
    const __bf16* gB1 = gB0 + (size_t)64 * ldb;
    __bf16* lA0 = &As[(wv << 4)][0];
    __bf16* lA1 = &As[64 + (wv << 4)][0];
    __bf16* lB0 = &Bs[(wv << 4)][0];
    __bf16* lB1 = &Bs[64 + (wv << 4)][0];

    f32x4 acc[4][4] = {};
    const int fr = ln & 15;
    const int fk = (ln >> 4) << 3;

    const int nSteps = kChunk >> 5;
    for (int ks = 0; ks < nSteps; ++ks) {
        gload_lds16(gA0, lA0);
        gload_lds16(gA1, lA1);
        gload_lds16(gB0, lB0);
        gload_lds16(gB1, lB1);
        gA0 += 32; gA1 += 32; gB0 += 32; gB1 += 32;
        __syncthreads();

        bf16x8 af[4], bfr[4];
        #pragma unroll
        for (int m = 0; m < 4; ++m)
            af[m] = *(const bf16x8*)&As[(wr << 6) + (m << 4) + fr][fk];
        #pragma unroll
        for (int n = 0; n < 4; ++n)
            bfr[n] = *(const bf16x8*)&Bs[(wc << 6) + (n << 4) + fr][fk];
        #pragma unroll
        for (int m = 0; m < 4; ++m)
            #pragma unroll
            for (int n = 0; n < 4; ++n)
                acc[m][n] = MFMA16(af[m], bfr[n], acc[m][n]);
        __syncthreads();
    }

    const int cr = (ln >> 4) << 2;
    const int cc = ln & 15;
    #pragma unroll
    for (int n = 0; n < 4; ++n) {
        const size_t col = n0 + (wc << 6) + (n << 4) + cc;
        #pragma unroll
        for (int m = 0; m < 4; ++m) {
            const size_t row = m0 + (wr << 6) + (m << 4) + cr;
            #pragma unroll
            for (int r = 0; r < 4; ++r)
                C[(row + r) * (size_t)ldc + col] = acc[m][n][r];
        }
    }
}

/* --------- per-token: softmax(LOG) -> w out; g -> XB tail cols --------- */
__global__ __launch_bounds__(64) void mole_softmax_g(
    const float* __restrict__ HP, const float* __restrict__ LOG,
    float* __restrict__ wOut, __bf16* __restrict__ XB)
{
    const int t   = blockIdx.x;
    const int tid = threadIdx.x;
    float h = 0.0f;
    #pragma unroll
    for (int sp = 0; sp < NSPLIT; ++sp)
        h += HP[((size_t)sp * BT + t) * 128 + 8 + tid];

    float lg[NEXP];
    #pragma unroll
    for (int e = 0; e < NEXP; ++e) lg[e] = LOG[(size_t)t * NEXP + e];
    float mx = lg[0];
    #pragma unroll
    for (int e = 1; e < NEXP; ++e) mx = fmaxf(mx, lg[e]);
    float ex[NEXP], den = 0.0f;
    #pragma unroll
    for (int e = 0; e < NEXP; ++e) { ex[e] = expf(lg[e] - mx); den += ex[e]; }

    const float w_my = ex[tid >> 3] / den;
    XB[(size_t)t * KX + DIN + tid] = (__bf16)(SCALING * w_my * h);
    if (tid < NEXP) wOut[(size_t)t * NEXP + tid] = ex[tid] / den;
}

/* ============ main 256x256 GEMM: ring-4 BK=32, counted vmcnt ============
   C[8192,2048] = XB[8192,KX] * WB[2048,KX]^T + bias
   8 waves (2M x 4N), per-wave 128x64 out. LDS = 4 ring slots x 32 KB
   ([A 256x32 | B 256x32] bf16, 64 B/row).
   Swizzle: phys16B(row,k) = k ^ ((row>>1)&3)  -> byte%128 takes 8 distinct
   values over any 8 consecutive rows => 2-way bank aliasing (free, m136).
   Applied via pre-swizzled global source; gload_lds dest stays linear.
   Per step: vmcnt(8) -> barrier -> 4 fb + 8 fa ds_read_b128 + 4 gload_lds
   (slot s+3) -> MFMAs with COMPILER-inserted fine-grained lgkmcnt (no
   forced drain; plain C++ ds_reads, so rule-18 does not apply). Loads stay
   3 steps in flight; never vmcnt(0) in main loop (T4). */
__global__ __launch_bounds__(512, 1) void mole_gemm256(
    const __bf16* __restrict__ XBp, const __bf16* __restrict__ WBp,
    float* __restrict__ C, const float* __restrict__ bias)
{
    __shared__ __align__(16) char smem[131072];

    const int tid = threadIdx.x;
    const int wv  = tid >> 6, l = tid & 63;
    const int wm  = wv >> 2, wn = wv & 3;
    const int bid = blockIdx.x;
    /* T1: XCD x (= bid&7) owns tm in [4x,4x+4) x all tn: 4 A-panels + 8
       B-panels = 13 MB L2-fill per XCD */
    const int xcd = bid & 7, ib = bid >> 3;
    const int tm = xcd * 4 + (ib & 3), tn = ib >> 2;
    const size_t m0 = (size_t)tm * 256, n0 = (size_t)tn * 256;

    /* staging: waves 0-3 stage A rows, waves 4-7 stage B rows.
       Per sub-tile instr: 16 rows x 64 B linear; lane l -> row +(l>>2),
       phys slot l&3 <- logical k-block (l&3) ^ ((l>>3)&3). */
    const int op = wv >> 2, ww = wv & 3;
    const __bf16* gstage = (op == 0 ? XBp + (m0 + ww * 64) * KX
                                    : WBp + (n0 + ww * 64) * KX)
                         + (size_t)(l >> 2) * KX + (((l & 3) ^ ((l >> 3) & 3)) << 3);
    const int stageBase = op * 16384 + ww * 4096;

    /* fragment read: row R, logical k-slot fq -> phys slot fq ^ ((R>>1)&3) */
    const int fr = l & 15, fq = l >> 4;
    const int swz = (fq ^ ((fr >> 1) & 3)) << 4;
    const int aByte = (wm * 128 + fr) * 64 + swz;
    const int bByte = 16384 + (wn * 64 + fr) * 64 + swz;

    f32x4 acc[8][4] = {};

    /* prologue: stage sub-tiles 0,1,2 (12 loads/thread) */
    #pragma unroll
    for (int s = 0; s < 3; ++s) {
        char* dst = smem + s * 32768 + stageBase;
        const __bf16* g = gstage + (size_t)s * 32;
        #pragma unroll
        for (int j = 0; j < 4; ++j)
            gload_lds16(g + (size_t)j * 16 * KX, dst + j * 1024);
    }

#define STEP(S, VMN, ST)                                                      \
    {                                                                         \
        asm volatile("s_waitcnt vmcnt(" #VMN ")" ::: "memory");               \
        __builtin_amdgcn_s_barrier();                                         \
        const char* slot = smem + ((S) & 3) * 32768;                          \
        bf16x8 fa[8], fb[4];                                                  \
        _Pragma("unroll")                                                     \
        for (int nf = 0; nf < 4; ++nf)                                        \
            fb[nf] = *(const bf16x8*)(slot + bByte + nf * 1024);              \
        _Pragma("unroll")                                                     \
        for (int mf = 0; mf < 8; ++mf)                                        \
            fa[mf] = *(const bf16x8*)(slot + aByte + mf * 1024);              \
        if (ST) {                                                             \
            char* dst = smem + (((S) + 3) & 3) * 32768 + stageBase;           \
            const __bf16* g = gstage + (size_t)((S) + 3) * 32;                \
            _Pragma("unroll")                                                 \
            for (int j = 0; j < 4; ++j)                                       \
                gload_lds16(g + (size_t)j * 16 * KX, dst + j * 1024);         \
        }                                                                     \
        __builtin_amdgcn_s_setprio(1);                                        \
        _Pragma("unroll")                                                     \
        for (int mf = 0; mf < 8; ++mf)                                        \
            _Pragma("unroll")                                                 \
            for (int nf = 0; nf < 4; ++nf)                                    \
                acc[mf][nf] = MFMA16(fa[mf], fb[nf], acc[mf][nf]);            \
        __builtin_amdgcn_s_setprio(0);                                        \
    }

    #pragma unroll 1
    for (int s = 0; s < NSUB - 3; ++s)
        STEP(s, 8, true);
    STEP(NSUB - 3, 8, false);
    STEP(NSUB - 2, 4, false);
    STEP(NSUB - 1, 0, false);
#undef STEP

    /* epilogue: C = acc + bias */
    const size_t crow = m0 + wm * 128 + fq * 4;
    const size_t ccol = n0 + wn * 64 + fr;
    #pragma unroll
    for (int nf = 0; nf < 4; ++nf) {
        const float bv = bias[ccol + nf * 16];
        #pragma unroll
        for (int mf = 0; mf < 8; ++mf) {
            float* cp = C + (crow + (size_t)mf * 16) * DOUT + ccol + nf * 16;
            #pragma unroll
            for (int i = 0; i < 4; ++i)
                cp[(size_t)i * DOUT] = acc[mf][nf][i] + bv;
        }
    }
}

extern "C" void kernel_launch(void* const* d_in, const int* in_sizes, int n_in,
                              void* d_out, int out_size, void* d_ws, size_t ws_size,
                              hipStream_t stream) {
    const float* x  = (const float*)d_in[0];
    const float* Wf = (const float*)d_in[1];
    const float* bf = (const float*)d_in[2];
    const float* Wr = (const float*)d_in[3];
    const float* br = (const float*)d_in[4];
    const float* A  = (const float*)d_in[5];
    const float* Bm = (const float*)d_in[6];

    float* out0 = (float*)d_out;
    float* wOut = out0 + (size_t)BT * DOUT;

    char* ws = (char*)d_ws;
    __bf16* XB   = (__bf16*)(ws + XB_OFF);
    __bf16* WB   = (__bf16*)(ws + WB_OFF);
    __bf16* ACAT = (__bf16*)(ws + ACAT_OFF);
    float*  HP   = (float*)(ws + HP_OFF);
    float*  LOG  = (float*)(ws + LOG_OFF);

    /* 1. weights -> bf16 layouts */
    mole_prep<<<4864, 256, 0, stream>>>(Wf, Bm, Wr, A, WB, ACAT);
    /* 2. x -> bf16 (stride KX) + exact fp32 router logits */
    mole_convert_x_logits<<<BT, 512, 0, stream>>>(x, Wr, br, XB, LOG);
    /* 3. h-cat = xb @ ACAT^T, 4-way K-split (256 blocks) */
    mole_gemm_bt<<<dim3(64, 1, NSPLIT), 256, 0, stream>>>(
        XB, KX, ACAT, DIN, HP, 128, DIN / NSPLIT, (long long)BT * 128);
    /* 4. softmax + g into XB tail columns; w to output */
    mole_softmax_g<<<BT, 64, 0, stream>>>(HP, LOG, wOut, XB);
    /* 5. out = [xb|g] @ [Wfb|Bcat]^T + bf  (K = 2112, ring-4 counted-vmcnt) */
    mole_gemm256<<<256, 512, 0, stream>>>(XB, WB, out0, bf);
}